// Round 9
// baseline (335.557 us; speedup 1.0000x reference)
//
#include <hip/hip_runtime.h>
#include <cstdint>
#include <cstddef>

// Problem constants
#define LSEQ 4096
#define DM 1024
#define DI 2048
#define DCONV 4
#define DRNK 64
#define DSTATE 16
#define DXW 96        // DRNK + 2*DSTATE
#define NCH 64        // r11: CLEN=32/NCH=128 regressed — keep 64
#define CLEN 64       // LSEQ / NCH
#define KSPLIT 8      // split-K for dbl GEMM

typedef unsigned short ushort_t;
typedef __bf16 bfx8 __attribute__((ext_vector_type(8)));
typedef float  fx2  __attribute__((ext_vector_type(2)));
typedef float  fx4  __attribute__((ext_vector_type(4)));
typedef float  fx16 __attribute__((ext_vector_type(16)));
typedef ushort_t usx8 __attribute__((ext_vector_type(8)));

__device__ __forceinline__ float siluf(float x) { return x / (1.f + __expf(-x)); }
__device__ __forceinline__ float softplusf(float x) {
  return fmaxf(x, 0.f) + log1pf(__expf(-fabsf(x)));
}
__device__ __forceinline__ ushort_t f2b(float x) {
  __bf16 b = (__bf16)x;   // RNE
  return __builtin_bit_cast(ushort_t, b);
}
__device__ __forceinline__ float b2f(ushort_t u) {
  unsigned int x = ((unsigned int)u) << 16;
  return __builtin_bit_cast(float, x);
}
__device__ __forceinline__ void async16(const void* g, void* l) {
  __builtin_amdgcn_global_load_lds(
      (const __attribute__((address_space(1))) unsigned int*)g,
      (__attribute__((address_space(3))) unsigned int*)l, 16, 0, 0);
}

// ---------------------------------------------------------------------------
// GEMM-1 (r17, FROZEN): chunk-granular register pipeline.
// LDS-throughput-bound — 96 ds_read_b128 x 12cyc + 384 conflict cyc + ~256
// DMA-write cyc = ~1800 cyc/tile wall vs MFMA 1030; measured 3000 (residual
// = latency/sync at 2 waves/SIMD). MfmaUtil 33% = 1030/3000.
// 256x256 tile, 512 thr (8 waves 2Mx4N, wave tile 128x64), BK=32, 4-slot
// LDS ring (128KB), stage t+2, counted vmcnt(4)/lgkmcnt(6), 1 barrier/tile.
// C/D: col=lane&31, row=(reg&3)+8*(reg>>2)+4*(lane>>5)  [m74/m101 verified].
// M%256==0, N%256==0, K%32==0, K/32>=3.
// ---------------------------------------------------------------------------
__global__ __launch_bounds__(512) void gemm_big(
    const ushort_t* __restrict__ A, int lda,
    const ushort_t* __restrict__ B, int ldb,
    ushort_t* __restrict__ C, int ldc, int K)
{
  __shared__ ushort_t As[4][256 * 32];
  __shared__ ushort_t Bs[4][256 * 32];

  const int tid  = threadIdx.x;
  // XCD-aware bijective swizzle (256 blocks, 8 XCDs -> 32 contiguous each)
  const int lid  = blockIdx.y * gridDim.x + blockIdx.x;
  const int sid  = (lid & 7) * 32 + (lid >> 3);
  const int m0   = (sid >> 4) * 256;
  const int n0   = (sid & 15) * 256;

  const int lane = tid & 63;
  const int wave = tid >> 6;           // 0..7
  const int wm   = (wave >> 2) * 128;  // 0,128
  const int wn   = (wave & 3) * 64;    // 0,64,128,192
  const int lm   = lane & 31;
  const int kg   = lane >> 5;
  const int key  = (lm >> 1) & 3;      // read-side XOR (rows 64B, 4 slots)

  const int r0   = tid >> 2;           // 0..127 staging row (per 128-row half)
  const int pos  = tid & 3;            // 16B chunk within 64B row
  const int cswz = (pos ^ ((r0 >> 1) & 3)) * 8;   // pre-swizzled global chunk

  fx16 acc[4][2] = {};
  bfx8 aE[4], bE[2], aO[4], bO[2];

  const ushort_t* ga = A + (size_t)(m0 + r0) * lda + cswz;
  const ushort_t* gb = B + (size_t)(n0 + r0) * ldb + cswz;

  const int NT = K >> 5;               // BK = 32

  auto stage4 = [&](int tile) {
    const int s = tile & 3;
    const int k = tile * 32;
#pragma unroll
    for (int h = 0; h < 2; ++h) {
      async16(ga + (size_t)(128 * h) * lda + k, &As[s][h * 128 * 32 + tid * 8]);
      async16(gb + (size_t)(128 * h) * ldb + k, &Bs[s][h * 128 * 32 + tid * 8]);
    }
  };
  auto read6 = [&](const ushort_t* as, const ushort_t* bs, int parity,
                   bfx8* af, bfx8* bfr) {
    const int swz = ((parity * 2 + kg) ^ key) * 8;
#pragma unroll
    for (int i = 0; i < 4; ++i)
      af[i] = *(const bfx8*)&as[(wm + i * 32 + lm) * 32 + swz];
#pragma unroll
    for (int j = 0; j < 2; ++j)
      bfr[j] = *(const bfx8*)&bs[(wn + j * 32 + lm) * 32 + swz];
  };
  auto mfma8 = [&](bfx8* af, bfx8* bfr) {
    __builtin_amdgcn_s_setprio(1);
#pragma unroll
    for (int i = 0; i < 4; ++i)
#pragma unroll
      for (int j = 0; j < 2; ++j)
        acc[i][j] = __builtin_amdgcn_mfma_f32_32x32x16_bf16(
            af[i], bfr[j], acc[i][j], 0, 0, 0);
    __builtin_amdgcn_s_setprio(0);
  };

  // prologue: tiles 0,1 staged (tile0's 4 loads oldest); tile0 landed -> read chunk0
  stage4(0);
  stage4(1);
  asm volatile("s_waitcnt vmcnt(4)" ::: "memory");   // tile0 landed
  __builtin_amdgcn_s_barrier();
  __builtin_amdgcn_sched_barrier(0);
  read6(&As[0][0], &Bs[0][0], 0, aE, bE);            // chunk 0 -> bank E

  for (int t = 0; t < NT; ++t) {
    const ushort_t* as = &As[t & 3][0];
    const ushort_t* bs = &Bs[t & 3][0];

    // chunk 2t+1 reads -> bank O (overlaps chunk 2t MFMA below)
    read6(as, bs, 1, aO, bO);
    if (t + 2 < NT) stage4(t + 2);
    __builtin_amdgcn_sched_barrier(0);
    asm volatile("s_waitcnt lgkmcnt(6)" ::: "memory");   // chunk 2t frags ready
    __builtin_amdgcn_sched_barrier(0);
    mfma8(aE, bE);                                       // chunk 2t
    __builtin_amdgcn_sched_barrier(0);

    // mid-iteration boundary: tile t+1 landed for all waves
    if (t + 2 < NT) asm volatile("s_waitcnt vmcnt(4)" ::: "memory");
    else            asm volatile("s_waitcnt vmcnt(0)" ::: "memory");
    __builtin_amdgcn_s_barrier();
    __builtin_amdgcn_sched_barrier(0);

    if (t + 1 < NT) {
      // chunk 2t+2 reads -> bank E (overlaps chunk 2t+1 MFMA below)
      read6(&As[(t + 1) & 3][0], &Bs[(t + 1) & 3][0], 0, aE, bE);
      __builtin_amdgcn_sched_barrier(0);
      asm volatile("s_waitcnt lgkmcnt(6)" ::: "memory"); // chunk 2t+1 ready
    } else {
      asm volatile("s_waitcnt lgkmcnt(0)" ::: "memory");
    }
    __builtin_amdgcn_sched_barrier(0);
    mfma8(aO, bO);                                       // chunk 2t+1
    __builtin_amdgcn_sched_barrier(0);
  }

#pragma unroll
  for (int i = 0; i < 4; ++i)
#pragma unroll
    for (int j = 0; j < 2; ++j)
#pragma unroll
      for (int r = 0; r < 16; ++r) {
        const int lrow = (r & 3) + 8 * (r >> 2) + 4 * kg;
        C[(size_t)(m0 + wm + i * 32 + lrow) * ldc + n0 + wn + j * 32 + lm] =
            f2b(acc[i][j][r]);
      }
}

// ---------------------------------------------------------------------------
// 32x32x16 bf16 MFMA NT GEMM, BK=64, 128xBN tile, 256 thr (r12/r13 lineage;
// GEMM-3, RESTORED r24). Both pipelined replacements (r18 128x128 1blk/CU,
// r23 128x64 2blk/CU) were neutral-to-worse: with 2 blocks/CU the old
// 2-barrier structure already gets inter-block overlap ~= the pipeline.
// EPI: 0 = f32 store, 1 = bf16 store.
// ---------------------------------------------------------------------------
template <int EPI, int BN>
__global__ __launch_bounds__(256) void gemm32(
    const ushort_t* __restrict__ A, int lda,
    const ushort_t* __restrict__ B, int ldb,
    void* __restrict__ Cv, int ldc, int K)
{
  constexpr int MI = 2;
  constexpr int NJ = BN / 64;          // 2 (BN=128) or 1 (BN=64)
  __shared__ ushort_t As[128 * 64];
  __shared__ ushort_t Bs[BN * 64];
  const int tid  = threadIdx.x;
  const int m0   = blockIdx.y * 128, n0 = blockIdx.x * BN;
  const int lane = tid & 63;
  const int wave = tid >> 6;
  const int wm   = (wave >> 1) * 64, wn = (wave & 1) * (BN / 2);
  const int lm   = lane & 31;
  const int kg   = lane >> 5;
  const int r0  = tid >> 3;
  const int pos = tid & 7;
  const int cswz = (pos ^ (r0 & 7)) * 8;
  const int key  = lm & 7;

  fx16 acc[MI][NJ] = {};

  const ushort_t* ga = A + (size_t)(m0 + r0) * lda + cswz;
  const ushort_t* gb = B + (size_t)(n0 + r0) * ldb + cswz;

  for (int k0 = 0; k0 < K; k0 += 64) {
#pragma unroll
    for (int t = 0; t < 4; ++t)
      async16(ga + (size_t)(32 * t) * lda + k0, &As[t * 32 * 64 + tid * 8]);
#pragma unroll
    for (int t = 0; t < BN / 32; ++t)
      async16(gb + (size_t)(32 * t) * ldb + k0, &Bs[t * 32 * 64 + tid * 8]);
    __syncthreads();

#pragma unroll
    for (int kk = 0; kk < 4; ++kk) {
      const int swz = ((kk * 2 + kg) ^ key) * 8;
      bfx8 af[MI], bfr[NJ];
#pragma unroll
      for (int i = 0; i < MI; ++i)
        af[i] = *(const bfx8*)&As[(wm + i * 32 + lm) * 64 + swz];
#pragma unroll
      for (int j = 0; j < NJ; ++j)
        bfr[j] = *(const bfx8*)&Bs[(wn + j * 32 + lm) * 64 + swz];
#pragma unroll
      for (int i = 0; i < MI; ++i)
#pragma unroll
        for (int j = 0; j < NJ; ++j)
          acc[i][j] = __builtin_amdgcn_mfma_f32_32x32x16_bf16(af[i], bfr[j], acc[i][j], 0, 0, 0);
    }
    __syncthreads();
  }

#pragma unroll
  for (int i = 0; i < MI; ++i)
#pragma unroll
    for (int j = 0; j < NJ; ++j)
#pragma unroll
      for (int r = 0; r < 16; ++r) {
        const int lrow = (r & 3) + 8 * (r >> 2) + 4 * kg;
        const size_t rowoff =
            (size_t)(m0 + wm + i * 32 + lrow) * ldc + n0 + wn + j * 32 + lm;
        if (EPI == 1) ((ushort_t*)Cv)[rowoff] = f2b(acc[i][j][r]);
        else          ((float*)Cv)[rowoff]   = acc[i][j][r];
      }
}

// ---------------------------------------------------------------------------
// Delta GEMM (r14; r19 in-scan fusion regressed +20us — keep separate).
// deltab = bf16(softplus(dtb @ W_dtb^T + b_dt)). K=64, 32x32 frags, 128x128.
// ---------------------------------------------------------------------------
__global__ __launch_bounds__(256) void gemm_delta(
    const ushort_t* __restrict__ A,      // dtb, lda=64
    const ushort_t* __restrict__ B,      // W_dtb, ldb=64
    const float* __restrict__ bias,
    ushort_t* __restrict__ C)            // deltab, ldc=DI
{
  __shared__ ushort_t As[128 * 64];
  __shared__ ushort_t Bs[128 * 64];
  const int tid  = threadIdx.x;
  const int m0   = blockIdx.y * 128, n0 = blockIdx.x * 128;
  const int lane = tid & 63;
  const int wave = tid >> 6;
  const int wm   = (wave >> 1) * 64, wn = (wave & 1) * 64;
  const int lm   = lane & 31;
  const int kg   = lane >> 5;
  const int r0  = tid >> 3;
  const int pos = tid & 7;
  const int cswz = (pos ^ (r0 & 7)) * 8;
  const int key  = lm & 7;

  fx16 acc[2][2] = {};

#pragma unroll
  for (int t = 0; t < 4; ++t)
    async16(A + (size_t)(m0 + r0 + 32 * t) * DRNK + cswz, &As[t * 32 * 64 + tid * 8]);
#pragma unroll
  for (int t = 0; t < 4; ++t)
    async16(B + (size_t)(n0 + r0 + 32 * t) * DRNK + cswz, &Bs[t * 32 * 64 + tid * 8]);
  __syncthreads();

#pragma unroll
  for (int kk = 0; kk < 4; ++kk) {
    const int swz = ((kk * 2 + kg) ^ key) * 8;
    bfx8 af[2], bfr[2];
#pragma unroll
    for (int i = 0; i < 2; ++i)
      af[i] = *(const bfx8*)&As[(wm + i * 32 + lm) * 64 + swz];
#pragma unroll
    for (int j = 0; j < 2; ++j)
      bfr[j] = *(const bfx8*)&Bs[(wn + j * 32 + lm) * 64 + swz];
#pragma unroll
    for (int i = 0; i < 2; ++i)
#pragma unroll
      for (int j = 0; j < 2; ++j)
        acc[i][j] = __builtin_amdgcn_mfma_f32_32x32x16_bf16(af[i], bfr[j], acc[i][j], 0, 0, 0);
  }

#pragma unroll
  for (int i = 0; i < 2; ++i)
#pragma unroll
    for (int j = 0; j < 2; ++j) {
      const int col = n0 + wn + j * 32 + lm;
      const float bv = bias[col];
#pragma unroll
      for (int r = 0; r < 16; ++r) {
        const int lrow = (r & 3) + 8 * (r >> 2) + 4 * kg;
        C[(size_t)(m0 + wm + i * 32 + lrow) * DI + col] =
            f2b(softplusf(acc[i][j][r] + bv));
      }
    }
}

// ---------------------------------------------------------------------------
// dbl GEMM (r15): 32x32 frags, BK=64. Tile 128(M)x96(N); 4 waves, wave-tile
// 32x96 (MI=1, NJ=3). partial[z][L,96] f32, plain stores.
// K-chunk per z = DI/KSPLIT = 256 -> 4 iters.
// ---------------------------------------------------------------------------
__global__ __launch_bounds__(256) void gemm_dbl(
    const ushort_t* __restrict__ A, const ushort_t* __restrict__ B,
    float* __restrict__ P)
{
  __shared__ ushort_t As[128 * 64];
  __shared__ ushort_t Bs[96 * 64];
  const int tid  = threadIdx.x;
  const int m0   = blockIdx.y * 128;
  const int lane = tid & 63;
  const int wave = tid >> 6;
  const int wm   = wave * 32;          // 0,32,64,96
  const int lm   = lane & 31;
  const int kg   = lane >> 5;
  const int r0  = tid >> 3;            // 0..31 rows per issue
  const int pos = tid & 7;
  const int cswz = (pos ^ (r0 & 7)) * 8;
  const int key  = lm & 7;
  const int kbeg = blockIdx.z * (DI / KSPLIT);

  fx16 acc[3] = {};

  const ushort_t* ga = A + (size_t)(m0 + r0) * DI + kbeg + cswz;
  const ushort_t* gb = B + (size_t)r0 * DI + kbeg + cswz;

  for (int k0 = 0; k0 < DI / KSPLIT; k0 += 64) {
#pragma unroll
    for (int t = 0; t < 4; ++t)
      async16(ga + (size_t)(32 * t) * DI + k0, &As[t * 32 * 64 + tid * 8]);
#pragma unroll
    for (int t = 0; t < 3; ++t)
      async16(gb + (size_t)(32 * t) * DI + k0, &Bs[t * 32 * 64 + tid * 8]);
    __syncthreads();

#pragma unroll
    for (int kk = 0; kk < 4; ++kk) {
      const int swz = ((kk * 2 + kg) ^ key) * 8;
      bfx8 af = *(const bfx8*)&As[(wm + lm) * 64 + swz];
      bfx8 bfr[3];
#pragma unroll
      for (int j = 0; j < 3; ++j)
        bfr[j] = *(const bfx8*)&Bs[(j * 32 + lm) * 64 + swz];
#pragma unroll
      for (int j = 0; j < 3; ++j)
        acc[j] = __builtin_amdgcn_mfma_f32_32x32x16_bf16(af, bfr[j], acc[j], 0, 0, 0);
    }
    __syncthreads();
  }

  float* base = P + (size_t)blockIdx.z * LSEQ * DXW;
#pragma unroll
  for (int j = 0; j < 3; ++j)
#pragma unroll
    for (int r = 0; r < 16; ++r) {
      const int lrow = (r & 3) + 8 * (r >> 2) + 4 * kg;
      base[(size_t)(m0 + wm + lrow) * DXW + j * 32 + lm] = acc[j][r];
    }
}

// ---------------------------------------------------------------------------
// reduce_dbl: sum KSPLIT partials; emit dtb = bf16(cols 0..63) and
// dblBC = f32 compact (cols 64..95 -> [l][32]). Deterministic z-order.
// ---------------------------------------------------------------------------
__global__ __launch_bounds__(256) void reduce_dbl(
    const float* __restrict__ P, ushort_t* __restrict__ dtb,
    float* __restrict__ dblBC)
{
  const int f = blockIdx.x * 256 + threadIdx.x;     // < LSEQ*DXW
  float s = 0.f;
#pragma unroll
  for (int z = 0; z < KSPLIT; ++z) s += P[(size_t)z * LSEQ * DXW + f];
  const int l = f / DXW;
  const int c = f - l * DXW;
  if (c < DRNK) dtb[(size_t)l * DRNK + c] = f2b(s);
  else          dblBC[(size_t)l * 32 + (c - DRNK)] = s;
}

// ---------------------------------------------------------------------------
// Fused cast of all 5 constant inputs to bf16 (one launch).
// ---------------------------------------------------------------------------
#define CSZ0 (LSEQ * DM)        // x       4194304
#define CSZ1 (2 * DI * DM)      // W_in    4194304
#define CSZ2 (DM * DI)          // W_out   2097152
#define CSZ3 (DXW * DI)         // W_x      196608
#define CSZ4 (DI * DRNK)        // W_dt     131072
#define CTOT (CSZ0 + CSZ1 + CSZ2 + CSZ3 + CSZ4)

__global__ __launch_bounds__(256) void cast_all(
    const float* __restrict__ x, const float* __restrict__ W_in,
    const float* __restrict__ W_out, const float* __restrict__ W_x,
    const float* __restrict__ W_dt,
    ushort_t* __restrict__ xb, ushort_t* __restrict__ W_inb,
    ushort_t* __restrict__ W_outb, ushort_t* __restrict__ W_xb,
    ushort_t* __restrict__ W_dtb)
{
  int i = (blockIdx.x * 256 + threadIdx.x) * 4;
  if (i >= CTOT) return;
  const float* src; ushort_t* dst;
  if (i < CSZ0) { src = x + i; dst = xb + i; }
  else if (i < CSZ0 + CSZ1) { int o = i - CSZ0; src = W_in + o; dst = W_inb + o; }
  else if (i < CSZ0 + CSZ1 + CSZ2) { int o = i - CSZ0 - CSZ1; src = W_out + o; dst = W_outb + o; }
  else if (i < CSZ0 + CSZ1 + CSZ2 + CSZ3) { int o = i - CSZ0 - CSZ1 - CSZ2; src = W_x + o; dst = W_xb + o; }
  else { int o = i - CSZ0 - CSZ1 - CSZ2 - CSZ3; src = W_dt + o; dst = W_dtb + o; }
  float4 v = *(const float4*)src;
  ushort4 o4;
  o4.x = f2b(v.x); o4.y = f2b(v.y); o4.z = f2b(v.z); o4.w = f2b(v.w);
  *(ushort4*)dst = o4;
}

// ---------------------------------------------------------------------------
// Sliding-window depthwise causal conv (k=4) + bias + silu, bf16 in/out.
// ---------------------------------------------------------------------------
__global__ __launch_bounds__(256) void conv2(
    const ushort_t* __restrict__ xrb, const float* __restrict__ cw,
    const float* __restrict__ cb, ushort_t* __restrict__ xsb)
{
  const int d0 = threadIdx.x * 8;
  const int l0 = blockIdx.x * 8;

  float4 w[8];
#pragma unroll
  for (int j = 0; j < 8; ++j) w[j] = *(const float4*)(cw + (size_t)(d0 + j) * DCONV);
  float cbv[8];
  *(float4*)&cbv[0] = *(const float4*)(cb + d0);
  *(float4*)&cbv[4] = *(const float4*)(cb + d0 + 4);

  float h0[8], h1[8], h2[8];
#pragma unroll
  for (int j = 0; j < 8; ++j) { h0[j] = 0.f; h1[j] = 0.f; h2[j] = 0.f; }
  if (l0 >= 3) {
    usx8 u0 = *(const usx8*)(xrb + (size_t)(l0 - 3) * (2 * DI) + d0);
    usx8 u1 = *(const usx8*)(xrb + (size_t)(l0 - 2) * (2 * DI) + d0);
    usx8 u2 = *(const usx8*)(xrb + (size_t)(l0 - 1) * (2 * DI) + d0);
#pragma unroll
    for (int j = 0; j < 8; ++j) { h0[j] = b2f(u0[j]); h1[j] = b2f(u1[j]); h2[j] = b2f(u2[j]); }
  }

#pragma unroll
  for (int i = 0; i < 8; ++i) {
    const int l = l0 + i;
    usx8 uc = *(const usx8*)(xrb + (size_t)l * (2 * DI) + d0);
    float c[8];
#pragma unroll
    for (int j = 0; j < 8; ++j) c[j] = b2f(uc[j]);
    usx8 o;
#pragma unroll
    for (int j = 0; j < 8; ++j) {
      float acc = cbv[j];
      acc = fmaf(w[j].x, h0[j], acc);
      acc = fmaf(w[j].y, h1[j], acc);
      acc = fmaf(w[j].z, h2[j], acc);
      acc = fmaf(w[j].w, c[j], acc);
      o[j] = f2b(siluf(acc));
    }
    *(usx8*)(xsb + (size_t)l * DI + d0) = o;
#pragma unroll
    for (int j = 0; j < 8; ++j) { h0[j] = h1[j]; h1[j] = h2[j]; h2[j] = c[j]; }
  }
}

// ---------------------------------------------------------------------------
// Chain detector: S4D-real init gives Av[n] = -(n+1) exactly, so
// dA[n] = q^(n+1), q = exp(-dlt): 1 exp + 16 muls instead of 16 exps.
// ---------------------------------------------------------------------------
__device__ __forceinline__ bool chain_ok(const float* Av) {
  bool ok = true;
#pragma unroll
  for (int n = 0; n < DSTATE; ++n)
    ok = ok && (fabsf(Av[n] + (float)(n + 1)) < 1e-4f);
  return ok;
}

// ---------------------------------------------------------------------------
// Scan pass 1 (r24): packed-FP32 n-loop. Scans are VALU-issue-bound (r19:
// VALUBusy 68%, HBM 8%, conflicts 0); gfx950 has full-rate v_pk_{fma,mul}_f32
// and LLVM selects them for <2 x float> code. h stored as fx2 h2[8]; chain
// advanced in pairs {q^(2k+1),q^(2k+2)} via *= {q2,q2} — cuts n-loop issue
// count ~2x (49 -> ~26 VALU/l). NOT bit-identical (pair-chain rounding),
// expected absmax ~1.46e-3 vs threshold 4.61e-3.
// ---------------------------------------------------------------------------
__global__ __launch_bounds__(256) void scan_pass1(
    const ushort_t* __restrict__ deltab, const ushort_t* __restrict__ xsb,
    const float* __restrict__ dblBC, const float* __restrict__ A_log,
    float* __restrict__ sd, float* __restrict__ cS)
{
  const int tid = threadIdx.x;
  const int g = blockIdx.x;            // dgroup (256 d's)
  const int c = blockIdx.y;            // chunk
  const int d = g * 256 + tid;
  __shared__ ushort_t Dsh[CLEN * 256];
  __shared__ ushort_t Ush[CLEN * 256];
  __shared__ float Bsh[CLEN][DSTATE];

  const size_t rowbase = (size_t)(c * CLEN) * DI + g * 256;
  for (int i = tid; i < CLEN * 32; i += 256) {
    const int l = i >> 5;
    const int o = (i & 31) * 8;
    *(usx8*)&Dsh[l * 256 + o] = *(const usx8*)(deltab + rowbase + (size_t)l * DI + o);
    *(usx8*)&Ush[l * 256 + o] = *(const usx8*)(xsb   + rowbase + (size_t)l * DI + o);
  }
  for (int i = tid; i < CLEN * DSTATE; i += 256) {
    const int l = i >> 4, n = i & 15;
    Bsh[l][n] = dblBC[(size_t)(c * CLEN + l) * 32 + n];
  }
  __syncthreads();

  float Av[DSTATE];
  fx2 h2[8];
#pragma unroll
  for (int n = 0; n < DSTATE; ++n) Av[n] = -__expf(A_log[d * DSTATE + n]);
#pragma unroll
  for (int k = 0; k < 8; ++k) h2[k] = fx2{0.f, 0.f};
  const size_t base = (size_t)c * DI * DSTATE + (size_t)d * DSTATE;
  float sdv = 0.f;

  if (chain_ok(Av)) {
#pragma unroll 2
    for (int l = 0; l < CLEN; ++l) {
      const float dlt = b2f(Dsh[l * 256 + tid]);
      const float du = dlt * b2f(Ush[l * 256 + tid]);
      sdv += dlt;
      const float q = __expf(-dlt);
      const float q2 = q * q;
      fx2 dv; dv.x = q; dv.y = q2;
      const fx2 qq = fx2{q2, q2};
      const fx2 duv = fx2{du, du};
#pragma unroll
      for (int k = 0; k < 8; ++k) {
        const fx2 b = *(const fx2*)&Bsh[l][2 * k];
        h2[k] = dv * h2[k] + duv * b;     // v_pk_fma_f32 + v_pk_mul_f32
        dv *= qq;
      }
    }
  } else {
    for (int l = 0; l < CLEN; ++l) {
      const float dlt = b2f(Dsh[l * 256 + tid]);
      const float du = dlt * b2f(Ush[l * 256 + tid]);
      sdv += dlt;
#pragma unroll
      for (int k = 0; k < 8; ++k) {
        const float dA0 = __expf(dlt * Av[2 * k]);
        const float dA1 = __expf(dlt * Av[2 * k + 1]);
        h2[k].x = fmaf(dA0, h2[k].x, du * Bsh[l][2 * k]);
        h2[k].y = fmaf(dA1, h2[k].y, du * Bsh[l][2 * k + 1]);
      }
    }
  }
  sd[(size_t)c * DI + d] = sdv;
#pragma unroll
  for (int k = 0; k < 8; ++k) *(fx2*)&cS[base + 2 * k] = h2[k];
}

// ---------------------------------------------------------------------------
// Scan pass 2 (r21 form, FROZEN): full register prefetch, static indexing.
// ---------------------------------------------------------------------------
__global__ __launch_bounds__(64) void scan_pass2(
    const float* __restrict__ sd, const float* __restrict__ cS,
    const float* __restrict__ A_log, float* __restrict__ ch0)
{
  const int dn = blockIdx.x * 64 + threadIdx.x;   // d*16+n
  const int d = dn >> 4;
  const float av = -__expf(A_log[dn]);
  float s[NCH], sdv[NCH];
#pragma unroll
  for (int c = 0; c < NCH; ++c) s[c] = cS[(size_t)c * DI * DSTATE + dn];
#pragma unroll
  for (int c = 0; c < NCH; ++c) sdv[c] = sd[(size_t)c * DI + d];
  float h = 0.f;
#pragma unroll
  for (int c = 0; c < NCH; ++c) {
    ch0[(size_t)c * DI * DSTATE + dn] = h;
    h = fmaf(__expf(av * sdv[c]), h, s[c]);
  }
}

// ---------------------------------------------------------------------------
// Scan pass 3 (r24): packed-FP32 n-loop (see pass1 header) + gate epilogue:
// y1b = bf16( (scan_y + u*D) * silu(res) ). y accumulated as fx2 pair,
// reduced at the end (16-term sum order changes: pairwise — within slack).
// ---------------------------------------------------------------------------
__global__ __launch_bounds__(256) void scan_pass3(
    const ushort_t* __restrict__ deltab, const ushort_t* __restrict__ xsb,
    const float* __restrict__ dblBC, const float* __restrict__ A_log,
    const float* __restrict__ ch0, const float* __restrict__ Dp,
    const ushort_t* __restrict__ xrb, ushort_t* __restrict__ y1b)
{
  const int tid = threadIdx.x;
  const int g = blockIdx.x;
  const int c = blockIdx.y;
  const int d = g * 256 + tid;
  __shared__ ushort_t Dsh[CLEN * 256];
  __shared__ ushort_t Ush[CLEN * 256];
  __shared__ float Bsh[CLEN][DSTATE];
  __shared__ float Csh[CLEN][DSTATE];

  const size_t rowbase = (size_t)(c * CLEN) * DI + g * 256;
  for (int i = tid; i < CLEN * 32; i += 256) {
    const int l = i >> 5;
    const int o = (i & 31) * 8;
    *(usx8*)&Dsh[l * 256 + o] = *(const usx8*)(deltab + rowbase + (size_t)l * DI + o);
    *(usx8*)&Ush[l * 256 + o] = *(const usx8*)(xsb   + rowbase + (size_t)l * DI + o);
  }
  for (int i = tid; i < CLEN * DSTATE; i += 256) {
    const int l = i >> 4, n = i & 15;
    const size_t row = (size_t)(c * CLEN + l) * 32;
    Bsh[l][n] = dblBC[row + n];
    Csh[l][n] = dblBC[row + 16 + n];
  }
  __syncthreads();

  float Av[DSTATE];
  fx2 h2[8];
  const size_t base = (size_t)c * DI * DSTATE + (size_t)d * DSTATE;
#pragma unroll
  for (int n = 0; n < DSTATE; ++n) Av[n] = -__expf(A_log[d * DSTATE + n]);
#pragma unroll
  for (int k = 0; k < 8; ++k) h2[k] = *(const fx2*)&ch0[base + 2 * k];
  const float Dd = Dp[d];
  const ushort_t* resp = xrb + (size_t)(c * CLEN) * (2 * DI) + DI + d;
  ushort_t* yp = y1b + (size_t)(c * CLEN) * DI + d;

  if (chain_ok(Av)) {
#pragma unroll 2
    for (int l = 0; l < CLEN; ++l) {
      const float dlt = b2f(Dsh[l * 256 + tid]);
      const float u = b2f(Ush[l * 256 + tid]);
      const float du = dlt * u;
      const float q = __expf(-dlt);
      const float q2 = q * q;
      fx2 dv; dv.x = q; dv.y = q2;
      const fx2 qq = fx2{q2, q2};
      const fx2 duv = fx2{du, du};
      fx2 y2 = fx2{0.f, 0.f};
#pragma unroll
      for (int k = 0; k < 8; ++k) {
        const fx2 b = *(const fx2*)&Bsh[l][2 * k];
        const fx2 cc = *(const fx2*)&Csh[l][2 * k];
        h2[k] = dv * h2[k] + duv * b;     // v_pk_fma_f32 + v_pk_mul_f32
        y2 = y2 + h2[k] * cc;             // v_pk_fma_f32
        dv *= qq;
      }
      float y = y2.x + y2.y;
      y = fmaf(u, Dd, y);
      const float res = b2f(resp[(size_t)l * (2 * DI)]);
      yp[(size_t)l * DI] = f2b(y * siluf(res));
    }
  } else {
    for (int l = 0; l < CLEN; ++l) {
      const float dlt = b2f(Dsh[l * 256 + tid]);
      const float u = b2f(Ush[l * 256 + tid]);
      const float du = dlt * u;
      float y = 0.f;
#pragma unroll
      for (int k = 0; k < 8; ++k) {
        const float dA0 = __expf(dlt * Av[2 * k]);
        const float dA1 = __expf(dlt * Av[2 * k + 1]);
        h2[k].x = fmaf(dA0, h2[k].x, du * Bsh[l][2 * k]);
        h2[k].y = fmaf(dA1, h2[k].y, du * Bsh[l][2 * k + 1]);
        y = fmaf(h2[k].x, Csh[l][2 * k], y);
        y = fmaf(h2[k].y, Csh[l][2 * k + 1], y);
      }
      y = fmaf(u, Dd, y);
      const float res = b2f(resp[(size_t)l * (2 * DI)]);
      yp[(size_t)l * DI] = f2b(y * siluf(res));
    }
  }
}

// ---------------------------------------------------------------------------
extern "C" void kernel_launch(void* const* d_in, const int* in_sizes, int n_in,
                              void* d_out, int out_size, void* d_ws, size_t ws_size,
                              hipStream_t stream) {
  (void)in_sizes; (void)n_in; (void)out_size; (void)ws_size;
  const float* x      = (const float*)d_in[0];
  const float* W_in   = (const float*)d_in[1];
  const float* conv_w = (const float*)d_in[2];
  const float* conv_b = (const float*)d_in[3];
  const float* W_x    = (const float*)d_in[4];
  const float* W_dt   = (const float*)d_in[5];
  const float* b_dt   = (const float*)d_in[6];
  const float* A_log  = (const float*)d_in[7];
  const float* Dp     = (const float*)d_in[8];
  const float* W_out  = (const float*)d_in[9];
  float* out = (float*)d_out;

  // workspace layout.
  // partial (KSPLIT*L*96 f = 12.6 MB) aliases [sd, cS, ch0] (17.3 MB):
  //   gemm_dbl writes partial -> reduce_dbl consumes -> delta-GEMM ->
  //   scan_pass1 writes sd/cS -> pass2 writes ch0. No live overlap.
  float* ws    = (float*)d_ws;
  float* sd    = ws;                                   // NCH*DI f = 0.5 MB
  float* cS    = sd + (size_t)NCH * DI;                // 8.4 MB
  float* ch0   = cS + (size_t)NCH * DI * DSTATE;       // 8.4 MB
  ushort_t* deltab = (ushort_t*)(ch0 + (size_t)NCH * DI * DSTATE);  // L*DI bf16
  ushort_t* xrb   = deltab + (size_t)LSEQ * DI;        // L*2DI
  ushort_t* xsb   = xrb   + (size_t)LSEQ * 2 * DI;     // L*DI
  ushort_t* y1b   = xsb   + (size_t)LSEQ * DI;         // L*DI
  ushort_t* xb    = y1b   + (size_t)LSEQ * DI;         // L*DM
  ushort_t* W_inb = xb    + (size_t)LSEQ * DM;         // 2DI*DM
  ushort_t* W_outb= W_inb + (size_t)2 * DI * DM;       // DM*DI
  ushort_t* W_xb  = W_outb+ (size_t)DM * DI;           // 96*DI
  ushort_t* W_dtb = W_xb  + (size_t)DXW * DI;          // DI*64
  ushort_t* dtb   = W_dtb + (size_t)DI * DRNK;         // L*64
  float* dblBC = (float*)(dtb + (size_t)LSEQ * DRNK);  // L*32 f
  float* partial = ws;   // alias (see above)

  // 0) all input casts in one launch
  hipLaunchKernelGGL(cast_all, dim3((CTOT / 4 + 255) / 256), dim3(256), 0, stream,
                     x, W_in, W_out, W_x, W_dt, xb, W_inb, W_outb, W_xb, W_dtb);

  // 1) xrb = bf16(x @ W_in.T)  (M=4096, N=4096, K=1024), 256x256 chunk-pipelined
  hipLaunchKernelGGL(gemm_big, dim3((2 * DI) / 256, LSEQ / 256), dim3(512), 0, stream,
                     xb, DM, W_inb, DM, xrb, 2 * DI, DM);

  // 2) xsb = bf16(silu(conv(xi) + b)) — sliding window
  hipLaunchKernelGGL(conv2, dim3(LSEQ / 8), dim3(256), 0, stream,
                     xrb, conv_w, conv_b, xsb);

  // 3) partial[z] = xsb @ W_xb.T chunk z; then reduce -> dtb bf16 + dblBC f32
  hipLaunchKernelGGL(gemm_dbl, dim3(1, LSEQ / 128, KSPLIT), dim3(256), 0, stream,
                     xsb, W_xb, partial);
  hipLaunchKernelGGL(reduce_dbl, dim3((LSEQ * DXW) / 256), dim3(256), 0, stream,
                     partial, dtb, dblBC);

  // 4) deltab = bf16(softplus(dtb @ W_dtb.T + b_dt)) — K=64 single-iter 32x32
  hipLaunchKernelGGL(gemm_delta, dim3(DI / 128, LSEQ / 128), dim3(256), 0, stream,
                     dtb, W_dtb, b_dt, deltab);

  // 5) chunked selective scan (3-pass, CLEN=64; sd-compressed carry state)
  hipLaunchKernelGGL(scan_pass1, dim3(DI / 256, NCH), dim3(256), 0, stream,
                     deltab, xsb, dblBC, A_log, sd, cS);
  hipLaunchKernelGGL(scan_pass2, dim3((DI * DSTATE) / 64), dim3(64), 0, stream,
                     sd, cS, A_log, ch0);
  hipLaunchKernelGGL(scan_pass3, dim3(DI / 256, NCH), dim3(256), 0, stream,
                     deltab, xsb, dblBC, A_log, ch0, Dp, xrb, y1b);

  // 6) out = y1b @ W_out.T  (M=4096, N=1024, K=2048), 32x32x16, BK=64
  hipLaunchKernelGGL(HIP_KERNEL_NAME(gemm32<0, 64>),
                     dim3(DM / 64, LSEQ / 128), dim3(256), 0, stream,
                     y1b, DI, W_outb, DI, (void*)out, DM, DI);
}

// Round 10
// 274.092 us; speedup vs baseline: 1.2242x; 1.2242x over previous
//
#include <hip/hip_runtime.h>
#include <cstdint>
#include <cstddef>

// Problem constants
#define LSEQ 4096
#define DM 1024
#define DI 2048
#define DCONV 4
#define DRNK 64
#define DSTATE 16
#define DXW 96        // DRNK + 2*DSTATE
#define NCH 64        // r11: CLEN=32/NCH=128 regressed — keep 64
#define CLEN 64       // LSEQ / NCH
#define KSPLIT 8      // split-K for dbl GEMM

typedef unsigned short ushort_t;
typedef __bf16 bfx8 __attribute__((ext_vector_type(8)));
typedef float  fx4  __attribute__((ext_vector_type(4)));
typedef float  fx16 __attribute__((ext_vector_type(16)));
typedef ushort_t usx8 __attribute__((ext_vector_type(8)));

__device__ __forceinline__ float siluf(float x) { return x / (1.f + __expf(-x)); }
__device__ __forceinline__ float softplusf(float x) {
  return fmaxf(x, 0.f) + log1pf(__expf(-fabsf(x)));
}
__device__ __forceinline__ ushort_t f2b(float x) {
  __bf16 b = (__bf16)x;   // RNE
  return __builtin_bit_cast(ushort_t, b);
}
__device__ __forceinline__ float b2f(ushort_t u) {
  unsigned int x = ((unsigned int)u) << 16;
  return __builtin_bit_cast(float, x);
}
__device__ __forceinline__ void async16(const void* g, void* l) {
  __builtin_amdgcn_global_load_lds(
      (const __attribute__((address_space(1))) unsigned int*)g,
      (__attribute__((address_space(3))) unsigned int*)l, 16, 0, 0);
}

// ---------------------------------------------------------------------------
// GEMM-1 (r17, FROZEN): chunk-granular register pipeline.
// LDS-throughput-bound — 96 ds_read_b128 x 12cyc + 384 conflict cyc + ~256
// DMA-write cyc = ~1800 cyc/tile wall vs MFMA 1030; measured 3000 (residual
// = latency/sync at 2 waves/SIMD). MfmaUtil 33% = 1030/3000.
// 256x256 tile, 512 thr (8 waves 2Mx4N, wave tile 128x64), BK=32, 4-slot
// LDS ring (128KB), stage t+2, counted vmcnt(4)/lgkmcnt(6), 1 barrier/tile.
// C/D: col=lane&31, row=(reg&3)+8*(reg>>2)+4*(lane>>5)  [m74/m101 verified].
// M%256==0, N%256==0, K%32==0, K/32>=3.
// ---------------------------------------------------------------------------
__global__ __launch_bounds__(512) void gemm_big(
    const ushort_t* __restrict__ A, int lda,
    const ushort_t* __restrict__ B, int ldb,
    ushort_t* __restrict__ C, int ldc, int K)
{
  __shared__ ushort_t As[4][256 * 32];
  __shared__ ushort_t Bs[4][256 * 32];

  const int tid  = threadIdx.x;
  // XCD-aware bijective swizzle (256 blocks, 8 XCDs -> 32 contiguous each)
  const int lid  = blockIdx.y * gridDim.x + blockIdx.x;
  const int sid  = (lid & 7) * 32 + (lid >> 3);
  const int m0   = (sid >> 4) * 256;
  const int n0   = (sid & 15) * 256;

  const int lane = tid & 63;
  const int wave = tid >> 6;           // 0..7
  const int wm   = (wave >> 2) * 128;  // 0,128
  const int wn   = (wave & 3) * 64;    // 0,64,128,192
  const int lm   = lane & 31;
  const int kg   = lane >> 5;
  const int key  = (lm >> 1) & 3;      // read-side XOR (rows 64B, 4 slots)

  const int r0   = tid >> 2;           // 0..127 staging row (per 128-row half)
  const int pos  = tid & 3;            // 16B chunk within 64B row
  const int cswz = (pos ^ ((r0 >> 1) & 3)) * 8;   // pre-swizzled global chunk

  fx16 acc[4][2] = {};
  bfx8 aE[4], bE[2], aO[4], bO[2];

  const ushort_t* ga = A + (size_t)(m0 + r0) * lda + cswz;
  const ushort_t* gb = B + (size_t)(n0 + r0) * ldb + cswz;

  const int NT = K >> 5;               // BK = 32

  auto stage4 = [&](int tile) {
    const int s = tile & 3;
    const int k = tile * 32;
#pragma unroll
    for (int h = 0; h < 2; ++h) {
      async16(ga + (size_t)(128 * h) * lda + k, &As[s][h * 128 * 32 + tid * 8]);
      async16(gb + (size_t)(128 * h) * ldb + k, &Bs[s][h * 128 * 32 + tid * 8]);
    }
  };
  auto read6 = [&](const ushort_t* as, const ushort_t* bs, int parity,
                   bfx8* af, bfx8* bfr) {
    const int swz = ((parity * 2 + kg) ^ key) * 8;
#pragma unroll
    for (int i = 0; i < 4; ++i)
      af[i] = *(const bfx8*)&as[(wm + i * 32 + lm) * 32 + swz];
#pragma unroll
    for (int j = 0; j < 2; ++j)
      bfr[j] = *(const bfx8*)&bs[(wn + j * 32 + lm) * 32 + swz];
  };
  auto mfma8 = [&](bfx8* af, bfx8* bfr) {
    __builtin_amdgcn_s_setprio(1);
#pragma unroll
    for (int i = 0; i < 4; ++i)
#pragma unroll
      for (int j = 0; j < 2; ++j)
        acc[i][j] = __builtin_amdgcn_mfma_f32_32x32x16_bf16(
            af[i], bfr[j], acc[i][j], 0, 0, 0);
    __builtin_amdgcn_s_setprio(0);
  };

  // prologue: tiles 0,1 staged (tile0's 4 loads oldest); tile0 landed -> read chunk0
  stage4(0);
  stage4(1);
  asm volatile("s_waitcnt vmcnt(4)" ::: "memory");   // tile0 landed
  __builtin_amdgcn_s_barrier();
  __builtin_amdgcn_sched_barrier(0);
  read6(&As[0][0], &Bs[0][0], 0, aE, bE);            // chunk 0 -> bank E

  for (int t = 0; t < NT; ++t) {
    const ushort_t* as = &As[t & 3][0];
    const ushort_t* bs = &Bs[t & 3][0];

    // chunk 2t+1 reads -> bank O (overlaps chunk 2t MFMA below)
    read6(as, bs, 1, aO, bO);
    if (t + 2 < NT) stage4(t + 2);
    __builtin_amdgcn_sched_barrier(0);
    asm volatile("s_waitcnt lgkmcnt(6)" ::: "memory");   // chunk 2t frags ready
    __builtin_amdgcn_sched_barrier(0);
    mfma8(aE, bE);                                       // chunk 2t
    __builtin_amdgcn_sched_barrier(0);

    // mid-iteration boundary: tile t+1 landed for all waves
    if (t + 2 < NT) asm volatile("s_waitcnt vmcnt(4)" ::: "memory");
    else            asm volatile("s_waitcnt vmcnt(0)" ::: "memory");
    __builtin_amdgcn_s_barrier();
    __builtin_amdgcn_sched_barrier(0);

    if (t + 1 < NT) {
      // chunk 2t+2 reads -> bank E (overlaps chunk 2t+1 MFMA below)
      read6(&As[(t + 1) & 3][0], &Bs[(t + 1) & 3][0], 0, aE, bE);
      __builtin_amdgcn_sched_barrier(0);
      asm volatile("s_waitcnt lgkmcnt(6)" ::: "memory"); // chunk 2t+1 ready
    } else {
      asm volatile("s_waitcnt lgkmcnt(0)" ::: "memory");
    }
    __builtin_amdgcn_sched_barrier(0);
    mfma8(aO, bO);                                       // chunk 2t+1
    __builtin_amdgcn_sched_barrier(0);
  }

#pragma unroll
  for (int i = 0; i < 4; ++i)
#pragma unroll
    for (int j = 0; j < 2; ++j)
#pragma unroll
      for (int r = 0; r < 16; ++r) {
        const int lrow = (r & 3) + 8 * (r >> 2) + 4 * kg;
        C[(size_t)(m0 + wm + i * 32 + lrow) * ldc + n0 + wn + j * 32 + lm] =
            f2b(acc[i][j][r]);
      }
}

// ---------------------------------------------------------------------------
// 32x32x16 bf16 MFMA NT GEMM, BK=64, 128xBN tile, 256 thr (r12/r13 lineage;
// GEMM-3). r18 gemm_out (128x128, 1 blk/CU, 1 wave/SIMD) was neutral-to-worse
// — reverted: 2 blocks/CU overlap here is worth as much as the pipeline.
// EPI: 0 = f32 store, 1 = bf16 store.
// ---------------------------------------------------------------------------
template <int EPI, int BN>
__global__ __launch_bounds__(256) void gemm32(
    const ushort_t* __restrict__ A, int lda,
    const ushort_t* __restrict__ B, int ldb,
    void* __restrict__ Cv, int ldc, int K)
{
  constexpr int MI = 2;
  constexpr int NJ = BN / 64;          // 2 (BN=128) or 1 (BN=64)
  __shared__ ushort_t As[128 * 64];
  __shared__ ushort_t Bs[BN * 64];
  const int tid  = threadIdx.x;
  const int m0   = blockIdx.y * 128, n0 = blockIdx.x * BN;
  const int lane = tid & 63;
  const int wave = tid >> 6;
  const int wm   = (wave >> 1) * 64, wn = (wave & 1) * (BN / 2);
  const int lm   = lane & 31;
  const int kg   = lane >> 5;
  const int r0  = tid >> 3;
  const int pos = tid & 7;
  const int cswz = (pos ^ (r0 & 7)) * 8;
  const int key  = lm & 7;

  fx16 acc[MI][NJ] = {};

  const ushort_t* ga = A + (size_t)(m0 + r0) * lda + cswz;
  const ushort_t* gb = B + (size_t)(n0 + r0) * ldb + cswz;

  for (int k0 = 0; k0 < K; k0 += 64) {
#pragma unroll
    for (int t = 0; t < 4; ++t)
      async16(ga + (size_t)(32 * t) * lda + k0, &As[t * 32 * 64 + tid * 8]);
#pragma unroll
    for (int t = 0; t < BN / 32; ++t)
      async16(gb + (size_t)(32 * t) * ldb + k0, &Bs[t * 32 * 64 + tid * 8]);
    __syncthreads();

#pragma unroll
    for (int kk = 0; kk < 4; ++kk) {
      const int swz = ((kk * 2 + kg) ^ key) * 8;
      bfx8 af[MI], bfr[NJ];
#pragma unroll
      for (int i = 0; i < MI; ++i)
        af[i] = *(const bfx8*)&As[(wm + i * 32 + lm) * 64 + swz];
#pragma unroll
      for (int j = 0; j < NJ; ++j)
        bfr[j] = *(const bfx8*)&Bs[(wn + j * 32 + lm) * 64 + swz];
#pragma unroll
      for (int i = 0; i < MI; ++i)
#pragma unroll
        for (int j = 0; j < NJ; ++j)
          acc[i][j] = __builtin_amdgcn_mfma_f32_32x32x16_bf16(af[i], bfr[j], acc[i][j], 0, 0, 0);
    }
    __syncthreads();
  }

#pragma unroll
  for (int i = 0; i < MI; ++i)
#pragma unroll
    for (int j = 0; j < NJ; ++j)
#pragma unroll
      for (int r = 0; r < 16; ++r) {
        const int lrow = (r & 3) + 8 * (r >> 2) + 4 * kg;
        const size_t rowoff =
            (size_t)(m0 + wm + i * 32 + lrow) * ldc + n0 + wn + j * 32 + lm;
        if (EPI == 1) ((ushort_t*)Cv)[rowoff] = f2b(acc[i][j][r]);
        else          ((float*)Cv)[rowoff]   = acc[i][j][r];
      }
}

// ---------------------------------------------------------------------------
// Delta GEMM (r14; r19 in-scan fusion regressed +20us — keep separate).
// deltab = bf16(softplus(dtb @ W_dtb^T + b_dt)). K=64, 32x32 frags, 128x128.
// ---------------------------------------------------------------------------
__global__ __launch_bounds__(256) void gemm_delta(
    const ushort_t* __restrict__ A,      // dtb, lda=64
    const ushort_t* __restrict__ B,      // W_dtb, ldb=64
    const float* __restrict__ bias,
    ushort_t* __restrict__ C)            // deltab, ldc=DI
{
  __shared__ ushort_t As[128 * 64];
  __shared__ ushort_t Bs[128 * 64];
  const int tid  = threadIdx.x;
  const int m0   = blockIdx.y * 128, n0 = blockIdx.x * 128;
  const int lane = tid & 63;
  const int wave = tid >> 6;
  const int wm   = (wave >> 1) * 64, wn = (wave & 1) * 64;
  const int lm   = lane & 31;
  const int kg   = lane >> 5;
  const int r0  = tid >> 3;
  const int pos = tid & 7;
  const int cswz = (pos ^ (r0 & 7)) * 8;
  const int key  = lm & 7;

  fx16 acc[2][2] = {};

#pragma unroll
  for (int t = 0; t < 4; ++t)
    async16(A + (size_t)(m0 + r0 + 32 * t) * DRNK + cswz, &As[t * 32 * 64 + tid * 8]);
#pragma unroll
  for (int t = 0; t < 4; ++t)
    async16(B + (size_t)(n0 + r0 + 32 * t) * DRNK + cswz, &Bs[t * 32 * 64 + tid * 8]);
  __syncthreads();

#pragma unroll
  for (int kk = 0; kk < 4; ++kk) {
    const int swz = ((kk * 2 + kg) ^ key) * 8;
    bfx8 af[2], bfr[2];
#pragma unroll
    for (int i = 0; i < 2; ++i)
      af[i] = *(const bfx8*)&As[(wm + i * 32 + lm) * 64 + swz];
#pragma unroll
    for (int j = 0; j < 2; ++j)
      bfr[j] = *(const bfx8*)&Bs[(wn + j * 32 + lm) * 64 + swz];
#pragma unroll
    for (int i = 0; i < 2; ++i)
#pragma unroll
      for (int j = 0; j < 2; ++j)
        acc[i][j] = __builtin_amdgcn_mfma_f32_32x32x16_bf16(af[i], bfr[j], acc[i][j], 0, 0, 0);
  }

#pragma unroll
  for (int i = 0; i < 2; ++i)
#pragma unroll
    for (int j = 0; j < 2; ++j) {
      const int col = n0 + wn + j * 32 + lm;
      const float bv = bias[col];
#pragma unroll
      for (int r = 0; r < 16; ++r) {
        const int lrow = (r & 3) + 8 * (r >> 2) + 4 * kg;
        C[(size_t)(m0 + wm + i * 32 + lrow) * DI + col] =
            f2b(softplusf(acc[i][j][r] + bv));
      }
    }
}

// ---------------------------------------------------------------------------
// dbl GEMM (r15): 32x32 frags, BK=64. Tile 128(M)x96(N); 4 waves, wave-tile
// 32x96 (MI=1, NJ=3). partial[z][L,96] f32, plain stores.
// K-chunk per z = DI/KSPLIT = 256 -> 4 iters.
// ---------------------------------------------------------------------------
__global__ __launch_bounds__(256) void gemm_dbl(
    const ushort_t* __restrict__ A, const ushort_t* __restrict__ B,
    float* __restrict__ P)
{
  __shared__ ushort_t As[128 * 64];
  __shared__ ushort_t Bs[96 * 64];
  const int tid  = threadIdx.x;
  const int m0   = blockIdx.y * 128;
  const int lane = tid & 63;
  const int wave = tid >> 6;
  const int wm   = wave * 32;          // 0,32,64,96
  const int lm   = lane & 31;
  const int kg   = lane >> 5;
  const int r0  = tid >> 3;            // 0..31 rows per issue
  const int pos = tid & 7;
  const int cswz = (pos ^ (r0 & 7)) * 8;
  const int key  = lm & 7;
  const int kbeg = blockIdx.z * (DI / KSPLIT);

  fx16 acc[3] = {};

  const ushort_t* ga = A + (size_t)(m0 + r0) * DI + kbeg + cswz;
  const ushort_t* gb = B + (size_t)r0 * DI + kbeg + cswz;

  for (int k0 = 0; k0 < DI / KSPLIT; k0 += 64) {
#pragma unroll
    for (int t = 0; t < 4; ++t)
      async16(ga + (size_t)(32 * t) * DI + k0, &As[t * 32 * 64 + tid * 8]);
#pragma unroll
    for (int t = 0; t < 3; ++t)
      async16(gb + (size_t)(32 * t) * DI + k0, &Bs[t * 32 * 64 + tid * 8]);
    __syncthreads();

#pragma unroll
    for (int kk = 0; kk < 4; ++kk) {
      const int swz = ((kk * 2 + kg) ^ key) * 8;
      bfx8 af = *(const bfx8*)&As[(wm + lm) * 64 + swz];
      bfx8 bfr[3];
#pragma unroll
      for (int j = 0; j < 3; ++j)
        bfr[j] = *(const bfx8*)&Bs[(j * 32 + lm) * 64 + swz];
#pragma unroll
      for (int j = 0; j < 3; ++j)
        acc[j] = __builtin_amdgcn_mfma_f32_32x32x16_bf16(af, bfr[j], acc[j], 0, 0, 0);
    }
    __syncthreads();
  }

  float* base = P + (size_t)blockIdx.z * LSEQ * DXW;
#pragma unroll
  for (int j = 0; j < 3; ++j)
#pragma unroll
    for (int r = 0; r < 16; ++r) {
      const int lrow = (r & 3) + 8 * (r >> 2) + 4 * kg;
      base[(size_t)(m0 + wm + lrow) * DXW + j * 32 + lm] = acc[j][r];
    }
}

// ---------------------------------------------------------------------------
// reduce_dbl: sum KSPLIT partials; emit dtb = bf16(cols 0..63) and
// dblBC = f32 compact (cols 64..95 -> [l][32]). Deterministic z-order.
// ---------------------------------------------------------------------------
__global__ __launch_bounds__(256) void reduce_dbl(
    const float* __restrict__ P, ushort_t* __restrict__ dtb,
    float* __restrict__ dblBC)
{
  const int f = blockIdx.x * 256 + threadIdx.x;     // < LSEQ*DXW
  float s = 0.f;
#pragma unroll
  for (int z = 0; z < KSPLIT; ++z) s += P[(size_t)z * LSEQ * DXW + f];
  const int l = f / DXW;
  const int c = f - l * DXW;
  if (c < DRNK) dtb[(size_t)l * DRNK + c] = f2b(s);
  else          dblBC[(size_t)l * 32 + (c - DRNK)] = s;
}

// ---------------------------------------------------------------------------
// Fused cast of all 5 constant inputs to bf16 (one launch).
// ---------------------------------------------------------------------------
#define CSZ0 (LSEQ * DM)        // x       4194304
#define CSZ1 (2 * DI * DM)      // W_in    4194304
#define CSZ2 (DM * DI)          // W_out   2097152
#define CSZ3 (DXW * DI)         // W_x      196608
#define CSZ4 (DI * DRNK)        // W_dt     131072
#define CTOT (CSZ0 + CSZ1 + CSZ2 + CSZ3 + CSZ4)

__global__ __launch_bounds__(256) void cast_all(
    const float* __restrict__ x, const float* __restrict__ W_in,
    const float* __restrict__ W_out, const float* __restrict__ W_x,
    const float* __restrict__ W_dt,
    ushort_t* __restrict__ xb, ushort_t* __restrict__ W_inb,
    ushort_t* __restrict__ W_outb, ushort_t* __restrict__ W_xb,
    ushort_t* __restrict__ W_dtb)
{
  int i = (blockIdx.x * 256 + threadIdx.x) * 4;
  if (i >= CTOT) return;
  const float* src; ushort_t* dst;
  if (i < CSZ0) { src = x + i; dst = xb + i; }
  else if (i < CSZ0 + CSZ1) { int o = i - CSZ0; src = W_in + o; dst = W_inb + o; }
  else if (i < CSZ0 + CSZ1 + CSZ2) { int o = i - CSZ0 - CSZ1; src = W_out + o; dst = W_outb + o; }
  else if (i < CSZ0 + CSZ1 + CSZ2 + CSZ3) { int o = i - CSZ0 - CSZ1 - CSZ2; src = W_x + o; dst = W_xb + o; }
  else { int o = i - CSZ0 - CSZ1 - CSZ2 - CSZ3; src = W_dt + o; dst = W_dtb + o; }
  float4 v = *(const float4*)src;
  ushort4 o4;
  o4.x = f2b(v.x); o4.y = f2b(v.y); o4.z = f2b(v.z); o4.w = f2b(v.w);
  *(ushort4*)dst = o4;
}

// ---------------------------------------------------------------------------
// Sliding-window depthwise causal conv (k=4) + bias + silu, bf16 in/out.
// ---------------------------------------------------------------------------
__global__ __launch_bounds__(256) void conv2(
    const ushort_t* __restrict__ xrb, const float* __restrict__ cw,
    const float* __restrict__ cb, ushort_t* __restrict__ xsb)
{
  const int d0 = threadIdx.x * 8;
  const int l0 = blockIdx.x * 8;

  float4 w[8];
#pragma unroll
  for (int j = 0; j < 8; ++j) w[j] = *(const float4*)(cw + (size_t)(d0 + j) * DCONV);
  float cbv[8];
  *(float4*)&cbv[0] = *(const float4*)(cb + d0);
  *(float4*)&cbv[4] = *(const float4*)(cb + d0 + 4);

  float h0[8], h1[8], h2[8];
#pragma unroll
  for (int j = 0; j < 8; ++j) { h0[j] = 0.f; h1[j] = 0.f; h2[j] = 0.f; }
  if (l0 >= 3) {
    usx8 u0 = *(const usx8*)(xrb + (size_t)(l0 - 3) * (2 * DI) + d0);
    usx8 u1 = *(const usx8*)(xrb + (size_t)(l0 - 2) * (2 * DI) + d0);
    usx8 u2 = *(const usx8*)(xrb + (size_t)(l0 - 1) * (2 * DI) + d0);
#pragma unroll
    for (int j = 0; j < 8; ++j) { h0[j] = b2f(u0[j]); h1[j] = b2f(u1[j]); h2[j] = b2f(u2[j]); }
  }

#pragma unroll
  for (int i = 0; i < 8; ++i) {
    const int l = l0 + i;
    usx8 uc = *(const usx8*)(xrb + (size_t)l * (2 * DI) + d0);
    float c[8];
#pragma unroll
    for (int j = 0; j < 8; ++j) c[j] = b2f(uc[j]);
    usx8 o;
#pragma unroll
    for (int j = 0; j < 8; ++j) {
      float acc = cbv[j];
      acc = fmaf(w[j].x, h0[j], acc);
      acc = fmaf(w[j].y, h1[j], acc);
      acc = fmaf(w[j].z, h2[j], acc);
      acc = fmaf(w[j].w, c[j], acc);
      o[j] = f2b(siluf(acc));
    }
    *(usx8*)(xsb + (size_t)l * DI + d0) = o;
#pragma unroll
    for (int j = 0; j < 8; ++j) { h0[j] = h1[j]; h1[j] = h2[j]; h2[j] = c[j]; }
  }
}

// ---------------------------------------------------------------------------
// Chain detector: S4D-real init gives Av[n] = -(n+1) exactly, so
// dA[n] = q^(n+1), q = exp(-dlt): 1 exp + 16 muls instead of 16 exps.
// ---------------------------------------------------------------------------
__device__ __forceinline__ bool chain_ok(const float* Av) {
  bool ok = true;
#pragma unroll
  for (int n = 0; n < DSTATE; ++n)
    ok = ok && (fabsf(Av[n] + (float)(n + 1)) < 1e-4f);
  return ok;
}

// ---------------------------------------------------------------------------
// Scan pass 1 (r21 form, FROZEN): LDS-staged, unroll-2 l-loop.
// r20 B-from-global regressed +16us at 2 waves/SIMD; r22 cooperative fusion
// failed correctness; r24 pk-float build regressed +61us (gemm_delta 90us,
// unexplained build interaction) — this scalar form is the verified best.
// ---------------------------------------------------------------------------
__global__ __launch_bounds__(256) void scan_pass1(
    const ushort_t* __restrict__ deltab, const ushort_t* __restrict__ xsb,
    const float* __restrict__ dblBC, const float* __restrict__ A_log,
    float* __restrict__ sd, float* __restrict__ cS)
{
  const int tid = threadIdx.x;
  const int g = blockIdx.x;            // dgroup (256 d's)
  const int c = blockIdx.y;            // chunk
  const int d = g * 256 + tid;
  __shared__ ushort_t Dsh[CLEN * 256];
  __shared__ ushort_t Ush[CLEN * 256];
  __shared__ float Bsh[CLEN][DSTATE];

  const size_t rowbase = (size_t)(c * CLEN) * DI + g * 256;
  for (int i = tid; i < CLEN * 32; i += 256) {
    const int l = i >> 5;
    const int o = (i & 31) * 8;
    *(usx8*)&Dsh[l * 256 + o] = *(const usx8*)(deltab + rowbase + (size_t)l * DI + o);
    *(usx8*)&Ush[l * 256 + o] = *(const usx8*)(xsb   + rowbase + (size_t)l * DI + o);
  }
  for (int i = tid; i < CLEN * DSTATE; i += 256) {
    const int l = i >> 4, n = i & 15;
    Bsh[l][n] = dblBC[(size_t)(c * CLEN + l) * 32 + n];
  }
  __syncthreads();

  float Av[DSTATE], h[DSTATE];
#pragma unroll
  for (int n = 0; n < DSTATE; ++n) {
    Av[n] = -__expf(A_log[d * DSTATE + n]);
    h[n] = 0.f;
  }
  const size_t base = (size_t)c * DI * DSTATE + (size_t)d * DSTATE;
  float sdv = 0.f;

  if (chain_ok(Av)) {
#pragma unroll 2
    for (int l = 0; l < CLEN; ++l) {
      const float dlt = b2f(Dsh[l * 256 + tid]);
      const float du = dlt * b2f(Ush[l * 256 + tid]);
      sdv += dlt;
      const float q = __expf(-dlt);
      float dAn = 1.f;
#pragma unroll
      for (int n = 0; n < DSTATE; ++n) {
        dAn *= q;
        h[n] = fmaf(dAn, h[n], du * Bsh[l][n]);
      }
    }
  } else {
    for (int l = 0; l < CLEN; ++l) {
      const float dlt = b2f(Dsh[l * 256 + tid]);
      const float du = dlt * b2f(Ush[l * 256 + tid]);
      sdv += dlt;
#pragma unroll
      for (int n = 0; n < DSTATE; ++n) {
        const float dA = __expf(dlt * Av[n]);
        h[n] = fmaf(dA, h[n], du * Bsh[l][n]);
      }
    }
  }
  sd[(size_t)c * DI + d] = sdv;
#pragma unroll
  for (int n = 0; n < DSTATE; ++n) cS[base + n] = h[n];
}

// ---------------------------------------------------------------------------
// Scan pass 2 (r21 form, FROZEN): full register prefetch, static indexing.
// ---------------------------------------------------------------------------
__global__ __launch_bounds__(64) void scan_pass2(
    const float* __restrict__ sd, const float* __restrict__ cS,
    const float* __restrict__ A_log, float* __restrict__ ch0)
{
  const int dn = blockIdx.x * 64 + threadIdx.x;   // d*16+n
  const int d = dn >> 4;
  const float av = -__expf(A_log[dn]);
  float s[NCH], sdv[NCH];
#pragma unroll
  for (int c = 0; c < NCH; ++c) s[c] = cS[(size_t)c * DI * DSTATE + dn];
#pragma unroll
  for (int c = 0; c < NCH; ++c) sdv[c] = sd[(size_t)c * DI + d];
  float h = 0.f;
#pragma unroll
  for (int c = 0; c < NCH; ++c) {
    ch0[(size_t)c * DI * DSTATE + dn] = h;
    h = fmaf(__expf(av * sdv[c]), h, s[c]);
  }
}

// ---------------------------------------------------------------------------
// Scan pass 3 (r21 form, FROZEN): LDS-staged + unroll 2 + gate epilogue:
// y1b = bf16( (scan_y + u*D) * silu(res) ).
// ---------------------------------------------------------------------------
__global__ __launch_bounds__(256) void scan_pass3(
    const ushort_t* __restrict__ deltab, const ushort_t* __restrict__ xsb,
    const float* __restrict__ dblBC, const float* __restrict__ A_log,
    const float* __restrict__ ch0, const float* __restrict__ Dp,
    const ushort_t* __restrict__ xrb, ushort_t* __restrict__ y1b)
{
  const int tid = threadIdx.x;
  const int g = blockIdx.x;
  const int c = blockIdx.y;
  const int d = g * 256 + tid;
  __shared__ ushort_t Dsh[CLEN * 256];
  __shared__ ushort_t Ush[CLEN * 256];
  __shared__ float Bsh[CLEN][DSTATE];
  __shared__ float Csh[CLEN][DSTATE];

  const size_t rowbase = (size_t)(c * CLEN) * DI + g * 256;
  for (int i = tid; i < CLEN * 32; i += 256) {
    const int l = i >> 5;
    const int o = (i & 31) * 8;
    *(usx8*)&Dsh[l * 256 + o] = *(const usx8*)(deltab + rowbase + (size_t)l * DI + o);
    *(usx8*)&Ush[l * 256 + o] = *(const usx8*)(xsb   + rowbase + (size_t)l * DI + o);
  }
  for (int i = tid; i < CLEN * DSTATE; i += 256) {
    const int l = i >> 4, n = i & 15;
    const size_t row = (size_t)(c * CLEN + l) * 32;
    Bsh[l][n] = dblBC[row + n];
    Csh[l][n] = dblBC[row + 16 + n];
  }
  __syncthreads();

  float Av[DSTATE], h[DSTATE];
  const size_t base = (size_t)c * DI * DSTATE + (size_t)d * DSTATE;
#pragma unroll
  for (int n = 0; n < DSTATE; ++n) {
    Av[n] = -__expf(A_log[d * DSTATE + n]);
    h[n] = ch0[base + n];
  }
  const float Dd = Dp[d];
  const ushort_t* resp = xrb + (size_t)(c * CLEN) * (2 * DI) + DI + d;
  ushort_t* yp = y1b + (size_t)(c * CLEN) * DI + d;

  if (chain_ok(Av)) {
#pragma unroll 2
    for (int l = 0; l < CLEN; ++l) {
      const float dlt = b2f(Dsh[l * 256 + tid]);
      const float u = b2f(Ush[l * 256 + tid]);
      const float du = dlt * u;
      const float q = __expf(-dlt);
      float dAn = 1.f;
      float y = 0.f;
#pragma unroll
      for (int n = 0; n < DSTATE; ++n) {
        dAn *= q;
        h[n] = fmaf(dAn, h[n], du * Bsh[l][n]);
        y = fmaf(h[n], Csh[l][n], y);
      }
      y = fmaf(u, Dd, y);
      const float res = b2f(resp[(size_t)l * (2 * DI)]);
      yp[(size_t)l * DI] = f2b(y * siluf(res));
    }
  } else {
    for (int l = 0; l < CLEN; ++l) {
      const float dlt = b2f(Dsh[l * 256 + tid]);
      const float u = b2f(Ush[l * 256 + tid]);
      const float du = dlt * u;
      float y = 0.f;
#pragma unroll
      for (int n = 0; n < DSTATE; ++n) {
        const float dA = __expf(dlt * Av[n]);
        h[n] = fmaf(dA, h[n], du * Bsh[l][n]);
        y = fmaf(h[n], Csh[l][n], y);
      }
      y = fmaf(u, Dd, y);
      const float res = b2f(resp[(size_t)l * (2 * DI)]);
      yp[(size_t)l * DI] = f2b(y * siluf(res));
    }
  }
}

// ---------------------------------------------------------------------------
extern "C" void kernel_launch(void* const* d_in, const int* in_sizes, int n_in,
                              void* d_out, int out_size, void* d_ws, size_t ws_size,
                              hipStream_t stream) {
  (void)in_sizes; (void)n_in; (void)out_size; (void)ws_size;
  const float* x      = (const float*)d_in[0];
  const float* W_in   = (const float*)d_in[1];
  const float* conv_w = (const float*)d_in[2];
  const float* conv_b = (const float*)d_in[3];
  const float* W_x    = (const float*)d_in[4];
  const float* W_dt   = (const float*)d_in[5];
  const float* b_dt   = (const float*)d_in[6];
  const float* A_log  = (const float*)d_in[7];
  const float* Dp     = (const float*)d_in[8];
  const float* W_out  = (const float*)d_in[9];
  float* out = (float*)d_out;

  // workspace layout.
  // partial (KSPLIT*L*96 f = 12.6 MB) aliases [sd, cS, ch0] (17.3 MB):
  //   gemm_dbl writes partial -> reduce_dbl consumes -> delta-GEMM ->
  //   scan_pass1 writes sd/cS -> pass2 writes ch0. No live overlap.
  float* ws    = (float*)d_ws;
  float* sd    = ws;                                   // NCH*DI f = 0.5 MB
  float* cS    = sd + (size_t)NCH * DI;                // 8.4 MB
  float* ch0   = cS + (size_t)NCH * DI * DSTATE;       // 8.4 MB
  ushort_t* deltab = (ushort_t*)(ch0 + (size_t)NCH * DI * DSTATE);  // L*DI bf16
  ushort_t* xrb   = deltab + (size_t)LSEQ * DI;        // L*2DI
  ushort_t* xsb   = xrb   + (size_t)LSEQ * 2 * DI;     // L*DI
  ushort_t* y1b   = xsb   + (size_t)LSEQ * DI;         // L*DI
  ushort_t* xb    = y1b   + (size_t)LSEQ * DI;         // L*DM
  ushort_t* W_inb = xb    + (size_t)LSEQ * DM;         // 2DI*DM
  ushort_t* W_outb= W_inb + (size_t)2 * DI * DM;       // DM*DI
  ushort_t* W_xb  = W_outb+ (size_t)DM * DI;           // 96*DI
  ushort_t* W_dtb = W_xb  + (size_t)DXW * DI;          // DI*64
  ushort_t* dtb   = W_dtb + (size_t)DI * DRNK;         // L*64
  float* dblBC = (float*)(dtb + (size_t)LSEQ * DRNK);  // L*32 f
  float* partial = ws;   // alias (see above)

  // 0) all input casts in one launch
  hipLaunchKernelGGL(cast_all, dim3((CTOT / 4 + 255) / 256), dim3(256), 0, stream,
                     x, W_in, W_out, W_x, W_dt, xb, W_inb, W_outb, W_xb, W_dtb);

  // 1) xrb = bf16(x @ W_in.T)  (M=4096, N=4096, K=1024), 256x256 chunk-pipelined
  hipLaunchKernelGGL(gemm_big, dim3((2 * DI) / 256, LSEQ / 256), dim3(512), 0, stream,
                     xb, DM, W_inb, DM, xrb, 2 * DI, DM);

  // 2) xsb = bf16(silu(conv(xi) + b)) — sliding window
  hipLaunchKernelGGL(conv2, dim3(LSEQ / 8), dim3(256), 0, stream,
                     xrb, conv_w, conv_b, xsb);

  // 3) partial[z] = xsb @ W_xb.T chunk z; then reduce -> dtb bf16 + dblBC f32
  hipLaunchKernelGGL(gemm_dbl, dim3(1, LSEQ / 128, KSPLIT), dim3(256), 0, stream,
                     xsb, W_xb, partial);
  hipLaunchKernelGGL(reduce_dbl, dim3((LSEQ * DXW) / 256), dim3(256), 0, stream,
                     partial, dtb, dblBC);

  // 4) deltab = bf16(softplus(dtb @ W_dtb.T + b_dt)) — K=64 single-iter 32x32
  hipLaunchKernelGGL(gemm_delta, dim3(DI / 128, LSEQ / 128), dim3(256), 0, stream,
                     dtb, W_dtb, b_dt, deltab);

  // 5) chunked selective scan (3-pass, CLEN=64; sd-compressed carry state)
  hipLaunchKernelGGL(scan_pass1, dim3(DI / 256, NCH), dim3(256), 0, stream,
                     deltab, xsb, dblBC, A_log, sd, cS);
  hipLaunchKernelGGL(scan_pass2, dim3((DI * DSTATE) / 64), dim3(64), 0, stream,
                     sd, cS, A_log, ch0);
  hipLaunchKernelGGL(scan_pass3, dim3(DI / 256, NCH), dim3(256), 0, stream,
                     deltab, xsb, dblBC, A_log, ch0, Dp, xrb, y1b);

  // 6) out = y1b @ W_out.T  (M=4096, N=1024, K=2048), 32x32x16, BK=64
  hipLaunchKernelGGL(HIP_KERNEL_NAME(gemm32<0, 64>),
                     dim3(DM / 64, LSEQ / 128), dim3(256), 0, stream,
                     y1b, DI, W_outb, DI, (void*)out, DM, DI);
}